// Round 1
// baseline (10.197 us; speedup 1.0000x reference)
//
#include <hip/hip_runtime.h>

// Game-of-Life rules as closed-form symmetric polynomial per pixel.
//
// Reference math (per pixel, torus 3x3 neighborhood, center prob a,
// 8 neighbor probs p_k):
//   main = a*P2 + P3                  (P_k = Poisson-binomial over 8 neighbors)
//   corr = w_c * E3q + q_c * G
//     q=p^2, r=(1-p)^2, w=p(1-p);  w_c=a(1-a), q_c=a^2
//     E3q = [t^3] prod_k (r_k + q_k t)
//     G   = [t^2 u] prod_k (r_k + q_k t + w_k u)
//   out = main - corr
//
// Symmetric in the 8 neighbors, so neighbor ordering is irrelevant.

__global__ __launch_bounds__(256)
void golr_kernel(const float* __restrict__ x, float* __restrict__ out) {
    constexpr int W = 256;
    constexpr int H = 256;
    const int row = blockIdx.x & (H - 1);
    const int b   = blockIdx.x >> 8;
    const int tx  = threadIdx.x;

    __shared__ float sh[3][W];

    const float* img = x + (size_t)b * H * W;
    const int ym = (row + H - 1) & (H - 1);
    const int yp = (row + 1) & (H - 1);

    sh[0][tx] = img[ym  * W + tx];
    sh[1][tx] = img[row * W + tx];
    sh[2][tx] = img[yp  * W + tx];
    __syncthreads();

    const int xm = (tx + W - 1) & (W - 1);
    const int xp = (tx + 1) & (W - 1);

    float n[9];
    n[0] = sh[0][xm]; n[1] = sh[0][tx]; n[2] = sh[0][xp];
    n[3] = sh[1][xm]; n[4] = sh[1][tx]; n[5] = sh[1][xp];
    n[6] = sh[2][xm]; n[7] = sh[2][tx]; n[8] = sh[2][xp];

    const float a = n[4];

    // DP1: elementary coeffs of prod_k ((1-p_k) + p_k t), degrees 0..3
    float c0 = 1.f, c1 = 0.f, c2 = 0.f, c3 = 0.f;
    // DP2: prod_k (r_k + q_k t + w_k u), track [t^j u^0] j=0..3 and [t^j u^1] j=0..2
    float d00 = 1.f, d10 = 0.f, d20 = 0.f, d30 = 0.f;
    float d01 = 0.f, d11 = 0.f, d21 = 0.f;

#pragma unroll
    for (int k = 0; k < 9; ++k) {
        if (k == 4) continue;  // center handled separately
        const float p  = n[k];
        const float np_ = 1.f - p;

        // DP1 (descending order: use old values)
        c3 = c3 * np_ + c2 * p;
        c2 = c2 * np_ + c1 * p;
        c1 = c1 * np_ + c0 * p;
        c0 = c0 * np_;

        const float q = p * p;
        const float r = np_ * np_;
        const float w = p * np_;

        // DP2 (descending in t; u-channel first since it reads u=0 olds)
        d21 = d21 * r + d11 * q + d20 * w;
        d11 = d11 * r + d01 * q + d10 * w;
        d01 = d01 * r + d00 * w;
        d30 = d30 * r + d20 * q;
        d20 = d20 * r + d10 * q;
        d10 = d10 * r + d00 * q;
        d00 = d00 * r;
    }

    const float main_ = a * c2 + c3;
    const float wc = a * (1.f - a);
    const float qc = a * a;
    const float corr = wc * d30 + qc * d21;

    out[(size_t)b * H * W + row * W + tx] = main_ - corr;
}

extern "C" void kernel_launch(void* const* d_in, const int* in_sizes, int n_in,
                              void* d_out, int out_size, void* d_ws, size_t ws_size,
                              hipStream_t stream) {
    const float* x = (const float*)d_in[0];
    float* out = (float*)d_out;
    // B*H blocks of W threads: 8*256 = 2048 blocks x 256
    golr_kernel<<<dim3(2048), dim3(256), 0, stream>>>(x, out);
}

// Round 2
// 9.959 us; speedup vs baseline: 1.0239x; 1.0239x over previous
//
#include <hip/hip_runtime.h>

// Game-of-Life rules, closed-form symmetric polynomial per pixel.
//
// Per pixel (center prob a, 8 neighbor probs p_k):
//   DP1: A(t) = prod_k ((1-p_k) + p_k t) = sum_i c_i t^i   (c_i = P(exactly i alive))
//   main = a*c2 + c3
//   Pair correction via factorization  r + q t + w u = ((1-p)+p s)((1-p)+p s'),
//   t = s s', u = s + s'  =>  DP2 poly = A(s) A(s'):
//     E3q = [t^3]   = c3^2 - 2(c6 c0 - c5 c1 + c4 c2)
//     G   = [t^2 u] = 5 c5 c0 - 3 c4 c1 + c3 c2
//   corr = a(1-a)*E3q + a^2*G
//   out  = main - corr

__global__ __launch_bounds__(256)
void golr_kernel(const float* __restrict__ x, float* __restrict__ out) {
    constexpr int W = 256, H = 256, R = 4;   // 4 output rows per block
    const int blk = blockIdx.x;              // 8 * (256/4) = 512 blocks
    const int b   = blk >> 6;                // blk / (H/R)
    const int rowbase = (blk & 63) * R;
    const int t    = threadIdx.x;
    const int wave = t >> 6;                 // 0..3 -> output row rowbase+wave
    const int lane = t & 63;                 // float4 column index

    __shared__ float sh[6][W];               // rows rowbase-1 .. rowbase+4

    const float* img = x + (size_t)b * H * W;

    // stage 6 rows x 64 float4 = 384 items with 256 threads
    for (int i = t; i < 6 * 64; i += 256) {
        const int ri = i >> 6, ci = i & 63;
        const int grow = (rowbase - 1 + ri + H) & (H - 1);
        ((float4*)sh[ri])[ci] = ((const float4*)(img + grow * W))[ci];
    }
    __syncthreads();

    const int c0i = lane * 4;
    const int liX = (c0i + W - 1) & (W - 1);
    const int riX = (c0i + 4) & (W - 1);

    // 6-wide windows of the 3 relevant rows
    float a6[3][6];
#pragma unroll
    for (int r = 0; r < 3; ++r) {
        const float* row = sh[wave + r];
        const float4 v = ((const float4*)row)[lane];
        a6[r][0] = row[liX];
        a6[r][1] = v.x; a6[r][2] = v.y; a6[r][3] = v.z; a6[r][4] = v.w;
        a6[r][5] = row[riX];
    }

    float o[4];
#pragma unroll
    for (int j = 0; j < 4; ++j) {
        float p8[8];
        p8[0] = a6[0][j]; p8[1] = a6[0][j + 1]; p8[2] = a6[0][j + 2];
        p8[3] = a6[1][j];                       p8[4] = a6[1][j + 2];
        p8[5] = a6[2][j]; p8[6] = a6[2][j + 1]; p8[7] = a6[2][j + 2];
        const float a = a6[1][j + 1];

        float c0 = 1.f, c1 = 0.f, c2 = 0.f, c3 = 0.f, c4 = 0.f, c5 = 0.f, c6 = 0.f;
#pragma unroll
        for (int k = 0; k < 8; ++k) {
            const float p = p8[k], np_ = 1.f - p;
            c6 = c6 * np_ + c5 * p;
            c5 = c5 * np_ + c4 * p;
            c4 = c4 * np_ + c3 * p;
            c3 = c3 * np_ + c2 * p;
            c2 = c2 * np_ + c1 * p;
            c1 = c1 * np_ + c0 * p;
            c0 = c0 * np_;
        }
        const float E3q  = c3 * c3 - 2.f * (c6 * c0 - c5 * c1 + c4 * c2);
        const float G    = 5.f * (c5 * c0) - 3.f * (c4 * c1) + c3 * c2;
        const float mn   = a * c2 + c3;
        const float corr = (a - a * a) * E3q + (a * a) * G;
        o[j] = mn - corr;
    }

    float4 ov;
    ov.x = o[0]; ov.y = o[1]; ov.z = o[2]; ov.w = o[3];
    ((float4*)(out + (size_t)b * H * W + (size_t)(rowbase + wave) * W))[lane] = ov;
}

extern "C" void kernel_launch(void* const* d_in, const int* in_sizes, int n_in,
                              void* d_out, int out_size, void* d_ws, size_t ws_size,
                              hipStream_t stream) {
    const float* x = (const float*)d_in[0];
    float* out = (float*)d_out;
    golr_kernel<<<dim3(512), dim3(256), 0, stream>>>(x, out);
}